// Round 1
// baseline (984.772 us; speedup 1.0000x reference)
//
#include <hip/hip_runtime.h>

#define B_ 8
#define S_ 1024
#define E_ 1024
#define H_ 16
#define D_ 64

typedef __attribute__((ext_vector_type(8))) short bf16x8;
typedef __attribute__((ext_vector_type(4))) float floatx4;

__device__ __forceinline__ floatx4 mfma16x16x32(bf16x8 a, bf16x8 b, floatx4 c) {
  return __builtin_amdgcn_mfma_f32_16x16x32_bf16(a, b, c, 0, 0, 0);
}

// f32 -> bf16 round-to-nearest-even
__device__ __forceinline__ unsigned short f2bf(float x) {
  unsigned int u = __builtin_bit_cast(unsigned int, x);
  u += 0x7FFFu + ((u >> 16) & 1u);
  return (unsigned short)(u >> 16);
}

// async global->LDS, 16 B per lane; LDS dest = wave-uniform base + lane*16
__device__ __forceinline__ void async16(const unsigned short* g, unsigned short* l) {
  __builtin_amdgcn_global_load_lds(
      (const __attribute__((address_space(1))) void*)g,
      (__attribute__((address_space(3))) void*)l, 16, 0, 0);
}

// ---------------------------------------------------------------------------
// key_padding_mask normalize (encoding-sniffing) -> additive 0 / -FLT_MAX
// ---------------------------------------------------------------------------
__global__ void mask_prep(const unsigned int* __restrict__ mraw, float* __restrict__ maskadd) {
  __shared__ int flagF, flagB;
  const int tid = threadIdx.x;
  if (tid == 0) { flagF = 0; flagB = 0; }
  __syncthreads();
  int lf = 0, lb = 0;
  for (int i = tid; i < 2048; i += 256) {
    unsigned int v = mraw[i];
    if (v == 0x3F800000u) lf = 1;
    else if (v > 1u) lb = 1;
  }
  if (lf) atomicOr(&flagF, 1);
  if (lb) atomicOr(&flagB, 1);
  __syncthreads();
  const unsigned char* mb = (const unsigned char*)mraw;
  const float* mf = (const float*)mraw;
  const int* mi = (const int*)mraw;
  const int fF = flagF, fB = flagB;
  for (int i = tid; i < B_ * S_; i += 256) {
    int pad;
    if (fF)      pad = (mf[i] != 0.0f);
    else if (fB) pad = (mb[i] != 0);
    else         pad = (mi[i] != 0);
    maskadd[i] = pad ? -3.4028234663852886e38f : 0.0f;
  }
}

// ---------------------------------------------------------------------------
// One-time f32 -> bf16 conversion: query (8M) + Wq/Wk/Wv/Wo (1M each)
// ---------------------------------------------------------------------------
__global__ __launch_bounds__(256) void convert_prep(
    const float* __restrict__ q, const float* __restrict__ wq, const float* __restrict__ wk,
    const float* __restrict__ wv, const float* __restrict__ wo,
    unsigned short* __restrict__ xb, unsigned short* __restrict__ wqb,
    unsigned short* __restrict__ wkb, unsigned short* __restrict__ wvb,
    unsigned short* __restrict__ wob)
{
  size_t idx = (size_t)blockIdx.x * 256 + threadIdx.x;   // vec4 index
  const float* src; unsigned short* dst; size_t off;
  if (idx < 2097152)      { src = q;  dst = xb;  off = idx; }
  else if (idx < 2359296) { src = wq; dst = wqb; off = idx - 2097152; }
  else if (idx < 2621440) { src = wk; dst = wkb; off = idx - 2359296; }
  else if (idx < 2883584) { src = wv; dst = wvb; off = idx - 2621440; }
  else                    { src = wo; dst = wob; off = idx - 2883584; }
  float4 v = *(const float4*)(src + off * 4);
  ushort4 u; u.x = f2bf(v.x); u.y = f2bf(v.y); u.z = f2bf(v.z); u.w = f2bf(v.w);
  *(ushort4*)(dst + off * 4) = u;
}

// ---------------------------------------------------------------------------
// m97-style bf16 GEMM core used by both projections.
// A [M x 1024] bf16 row-major, B [N x 1024] bf16 row-major (out = A B^T).
// 128x128 tile, BK=64, global_load_lds width 16, XOR-swizzled LDS
// (chunk' = chunk ^ (row&7)) -> 2-way-only bank aliasing on ds_read_b128.
// ---------------------------------------------------------------------------
__device__ __forceinline__ void gemm_core(
    const unsigned short* __restrict__ A, const unsigned short* __restrict__ Bm,
    int m0, int n0, unsigned short* As, unsigned short* Bs, floatx4 (&acc)[4][4])
{
  const int tid = threadIdx.x;
  const int wave = tid >> 6, lane = tid & 63;
  const int quad = lane >> 4, l16 = lane & 15;
  const int mb = (wave >> 1) * 64, nb = (wave & 1) * 64;
  const int ldrow = lane >> 3;              // 0..7 within 8-row group
  const int gchunk = (lane & 7) ^ ldrow;    // swizzled source chunk

  for (int ks = 0; ks < 16; ++ks) {
    const int k0 = ks * 64;
    __syncthreads();
    for (int is = 0; is < 4; ++is) {
      int issue = wave * 4 + is;
      async16(A + (size_t)(m0 + issue * 8 + ldrow) * 1024 + k0 + gchunk * 8, &As[issue * 512]);
      async16(Bm + (size_t)(n0 + issue * 8 + ldrow) * 1024 + k0 + gchunk * 8, &Bs[issue * 512]);
    }
    __syncthreads();
    for (int kk = 0; kk < 2; ++kk) {
      const int pc = ((quad + 4 * kk) ^ (l16 & 7)) * 8;
      bf16x8 af[4], bfm[4];
      for (int i = 0; i < 4; ++i)
        af[i] = *(const bf16x8*)(&As[(mb + 16 * i + l16) * 64 + pc]);
      for (int j = 0; j < 4; ++j)
        bfm[j] = *(const bf16x8*)(&Bs[(nb + 16 * j + l16) * 64 + pc]);
      for (int i = 0; i < 4; ++i)
        for (int j = 0; j < 4; ++j)
          acc[i][j] = mfma16x16x32(af[i], bfm[j], acc[i][j]);
    }
  }
}

// QKV projection: N-tiles 0..7 -> q (scaled), 8..15 -> k, 16..23 -> v (transposed store)
// Epilogue stages the 128x128 tile in LDS and writes 128B-contiguous runs.
__global__ __launch_bounds__(256) void gemm_qkv(
    const unsigned short* __restrict__ Xbf,
    const unsigned short* __restrict__ Wqb, const unsigned short* __restrict__ Wkb,
    const unsigned short* __restrict__ Wvb,
    const float* __restrict__ bq, const float* __restrict__ bk, const float* __restrict__ bv,
    unsigned short* __restrict__ qo, unsigned short* __restrict__ ko, unsigned short* __restrict__ vo)
{
  const int tid = threadIdx.x;
  // T1 XCD swizzle (1536 blocks, 1536%8==0 -> simple form is bijective)
  const int flat = blockIdx.y * 24 + blockIdx.x;
  const int swz = (flat & 7) * 192 + (flat >> 3);
  const int bx = swz % 24, by = swz / 24;
  const int n0 = bx * 128;
  const int m0 = by * 128;
  const int which = n0 >> 10;
  const int nn0 = n0 & 1023;
  const unsigned short* W = (which == 0) ? Wqb : (which == 1) ? Wkb : Wvb;
  const float* bias = (which == 0) ? bq : (which == 1) ? bk : bv;

  // 34816 B: [0,8192)=As, [8192,16384)=Bs during K-loop; whole buffer as
  // padded 128x136 u16 tile in the epilogue (time-disjoint).
  __shared__ unsigned short smem[128 * 136];
  unsigned short* As = smem;
  unsigned short* Bs = smem + 8192;

  const int lane = tid & 63, wave = tid >> 6;
  const int quad = lane >> 4, l16 = lane & 15;
  const int mb = (wave >> 1) * 64, nb = (wave & 1) * 64;

  floatx4 z = {0.f, 0.f, 0.f, 0.f};
  floatx4 acc[4][4];
  for (int i = 0; i < 4; ++i) for (int j = 0; j < 4; ++j) acc[i][j] = z;

  gemm_core(Xbf, W, m0, nn0, As, Bs, acc);

  float bv4[4];
  for (int j = 0; j < 4; ++j) bv4[j] = bias[nn0 + nb + 16 * j + l16];

  __syncthreads();   // all waves done reading As/Bs

  const float scale = (which == 0) ? 0.125f : 1.0f;
  if (which < 2) {
    // stage [m][n] (row stride 136 u16 keeps b128 reads 16B-aligned)
    #pragma unroll
    for (int i = 0; i < 4; ++i)
      #pragma unroll
      for (int r = 0; r < 4; ++r) {
        const int mr = mb + 16 * i + quad * 4 + r;
        #pragma unroll
        for (int j = 0; j < 4; ++j)
          smem[mr * 136 + nb + 16 * j + l16] = f2bf((acc[i][j][r] + bv4[j]) * scale);
      }
  } else {
    // stage transposed [n][m] for the v^T layout
    #pragma unroll
    for (int i = 0; i < 4; ++i)
      #pragma unroll
      for (int r = 0; r < 4; ++r) {
        const int mr = mb + 16 * i + quad * 4 + r;
        #pragma unroll
        for (int j = 0; j < 4; ++j)
          smem[(nb + 16 * j + l16) * 136 + mr] = f2bf(acc[i][j][r] + bv4[j]);
      }
  }
  __syncthreads();

  const int row = tid >> 1, half = tid & 1;   // 128 rows x 2 half-rows of 64 u16
  if (which < 2) {
    const int m = m0 + row, bb = m >> 10, s = m & 1023;
    const int hh = (nn0 >> 6) + half;
    unsigned short* dst = ((which == 0) ? qo : ko) +
        ((size_t)(bb * 16 + hh) * 1024 + s) * 64;
    #pragma unroll
    for (int c = 0; c < 8; ++c)
      *(bf16x8*)(dst + c * 8) = *(const bf16x8*)(&smem[row * 136 + half * 64 + c * 8]);
  } else {
    const int nglob = nn0 + row;
    const int hh = nglob >> 6, d = nglob & 63;
    const int bb = m0 >> 10;                  // m0 mult of 128 -> tile within one b
    unsigned short* dst = vo + ((size_t)(bb * 16 + hh) * 64 + d) * 1024 +
        (m0 & 1023) + half * 64;
    #pragma unroll
    for (int c = 0; c < 8; ++c)
      *(bf16x8*)(dst + c * 8) = *(const bf16x8*)(&smem[row * 136 + half * 64 + c * 8]);
  }
}

// Output projection: out = attn @ Wo.T + bo, f32 out
__global__ __launch_bounds__(256) void gemm_out(
    const unsigned short* __restrict__ Abf, const unsigned short* __restrict__ Wob,
    const float* __restrict__ bo, float* __restrict__ out)
{
  const int flat = blockIdx.y * 8 + blockIdx.x;   // 512 blocks
  const int swz = (flat & 7) * 64 + (flat >> 3);
  const int n0 = (swz & 7) * 128;
  const int m0 = (swz >> 3) * 128;
  __shared__ unsigned short As[128 * 64];
  __shared__ unsigned short Bs[128 * 64];

  const int lane = threadIdx.x & 63, wave = threadIdx.x >> 6;
  const int quad = lane >> 4, l16 = lane & 15;
  const int mb = (wave >> 1) * 64, nb = (wave & 1) * 64;

  floatx4 z = {0.f, 0.f, 0.f, 0.f};
  floatx4 acc[4][4];
  for (int i = 0; i < 4; ++i) for (int j = 0; j < 4; ++j) acc[i][j] = z;

  gemm_core(Abf, Wob, m0, n0, As, Bs, acc);

  for (int i = 0; i < 4; ++i) {
    for (int r = 0; r < 4; ++r) {
      int m = m0 + mb + 16 * i + quad * 4 + r;
      for (int j = 0; j < 4; ++j) {
        int n = n0 + nb + 16 * j + l16;
        out[(size_t)m * 1024 + n] = acc[i][j][r] + bo[n];
      }
    }
  }
}

// ---------------------------------------------------------------------------
// Flash attention, occupancy-first version.
// Changes vs prior: the 68 KB sc[] LDS bias tile is GONE. Each lane loads its
// MFMA C-init elements (row=quad*4+r, col=16t+l16) directly from global in
// C-fragment layout (64B-coalesced), pre-summed bias+amask+maskadd into 16
// registers, double-buffered one k-tile ahead. LDS: 87 KB -> 17.4 KB
// (Vt 8K + P_lds 9K) -> 3-4 blocks/CU instead of 1.
// ---------------------------------------------------------------------------
__global__ __launch_bounds__(256) void attn_fwd(
    const unsigned short* __restrict__ qw, const unsigned short* __restrict__ kw,
    const unsigned short* __restrict__ vw, const float* __restrict__ bias,
    const float* __restrict__ amask, const float* __restrict__ maskadd,
    unsigned short* __restrict__ attnw)
{
  const int tid = threadIdx.x;
  const int wave = tid >> 6, lane = tid & 63;
  const int quad = lane >> 4, l16 = lane & 15;
  // T1 XCD swizzle: all 16 q-tiles of one bh land on the same XCD -> K/V L2 hits
  const int flat = blockIdx.y * 16 + blockIdx.x;   // 2048 blocks
  const int swz = (flat & 7) * 256 + (flat >> 3);
  const int qt = swz & 15, bh = swz >> 4;
  const int b = bh >> 4, h = bh & 15;
  const int qbase = qt * 64 + wave * 16;

  const unsigned short* qh = qw + (size_t)bh * (S_ * D_);
  const unsigned short* kh = kw + (size_t)bh * (S_ * D_);
  const unsigned short* vh = vw + (size_t)bh * (S_ * D_);
  // row bases pre-offset to this wave's quad-group of 4 q-rows
  const float* biasb = bias + (size_t)bh * ((size_t)S_ * S_) +
                       (size_t)(qt * 64 + wave * 16 + quad * 4) * S_;
  const float* amrow = amask + (size_t)(qt * 64 + wave * 16 + quad * 4) * S_;
  const float* madd  = maskadd + b * S_;

  __shared__ unsigned short Vt[64 * 64];        // V^T tile, XOR-swizzled
  __shared__ unsigned short P_lds[4 * 16 * 72];
  unsigned short* Pw = &P_lds[wave * (16 * 72)];

  const int vrow = tid >> 3;                    // 0..31 (x2 issues) = d row
  const int vchk = tid & 7;                     // physical 8-key chunk

  // Q fragments resident for whole kernel
  bf16x8 aQ0 = *(const bf16x8*)(qh + (size_t)(qbase + l16) * 64 + quad * 8);
  bf16x8 aQ1 = *(const bf16x8*)(qh + (size_t)(qbase + l16) * 64 + 32 + quad * 8);

  bf16x8 pv[2];
  float cc[4][4], nc[4][4];                     // C-init double buffer (16+16 regs)

  auto load_v = [&](int key0) {
    #pragma unroll
    for (int i2 = 0; i2 < 2; ++i2) {
      int d = vrow + 32 * i2;
      int gc = vchk ^ (d & 7);
      pv[i2] = *(const bf16x8*)(vh + (size_t)d * 1024 + key0 + gc * 8);
    }
  };
  auto load_cinit = [&](int key0, float (&dst)[4][4]) {
    #pragma unroll
    for (int t = 0; t < 4; ++t) {
      const int col = key0 + 16 * t + l16;
      const float mv = madd[col];
      #pragma unroll
      for (int r = 0; r < 4; ++r)
        dst[t][r] = biasb[(size_t)r * S_ + col] + amrow[(size_t)r * S_ + col] + mv;
    }
  };
  load_v(0);
  load_cinit(0, cc);

  floatx4 zz = {0.f, 0.f, 0.f, 0.f};
  floatx4 oacc[4] = {zz, zz, zz, zz};
  float m_run[4], l_run[4];
  for (int r = 0; r < 4; ++r) { m_run[r] = -__builtin_inff(); l_run[r] = 0.f; }

  for (int kt = 0; kt < 16; ++kt) {
    const int key0 = kt * 64;
    __syncthreads();                            // Vt free (prev PV done)
    #pragma unroll
    for (int i2 = 0; i2 < 2; ++i2)
      *(bf16x8*)(&Vt[(vrow + 32 * i2) * 64 + vchk * 8]) = pv[i2];

    // K fragments for THIS tile
    bf16x8 bK0[4], bK1[4];
    #pragma unroll
    for (int t = 0; t < 4; ++t) {
      const unsigned short* kr = kh + (size_t)(key0 + 16 * t + l16) * 64;
      bK0[t] = *(const bf16x8*)(kr + quad * 8);
      bK1[t] = *(const bf16x8*)(kr + 32 + quad * 8);
    }
    // prefetch next tile's V regs + C-init regs (consumed after next barrier)
    if (kt < 15) { load_v(key0 + 64); load_cinit(key0 + 64, nc); }
    __syncthreads();                            // Vt visible

    // scores: C-init from registers, then QK^T
    floatx4 sfr[4];
    #pragma unroll
    for (int t = 0; t < 4; ++t) {
      floatx4 c;
      #pragma unroll
      for (int r = 0; r < 4; ++r) c[r] = cc[t][r];
      c = mfma16x16x32(aQ0, bK0[t], c);
      c = mfma16x16x32(aQ1, bK1[t], c);
      sfr[t] = c;
    }
    // online softmax (16-lane quad reductions)
    #pragma unroll
    for (int r = 0; r < 4; ++r) {
      float rm = fmaxf(fmaxf(sfr[0][r], sfr[1][r]), fmaxf(sfr[2][r], sfr[3][r]));
      rm = fmaxf(rm, __shfl_xor(rm, 1));
      rm = fmaxf(rm, __shfl_xor(rm, 2));
      rm = fmaxf(rm, __shfl_xor(rm, 4));
      rm = fmaxf(rm, __shfl_xor(rm, 8));
      float mnew = fmaxf(m_run[r], rm);
      float alpha = __expf(m_run[r] - mnew);
      float psum = 0.f;
      #pragma unroll
      for (int t = 0; t < 4; ++t) {
        float p = __expf(sfr[t][r] - mnew);
        psum += p;
        Pw[(quad * 4 + r) * 72 + 16 * t + l16] = f2bf(p);
      }
      psum += __shfl_xor(psum, 1);
      psum += __shfl_xor(psum, 2);
      psum += __shfl_xor(psum, 4);
      psum += __shfl_xor(psum, 8);
      l_run[r] = l_run[r] * alpha + psum;
      m_run[r] = mnew;
      oacc[0][r] *= alpha; oacc[1][r] *= alpha; oacc[2][r] *= alpha; oacc[3][r] *= alpha;
    }
    // O += P V from LDS (wave-local P: lgkm ordering only, no barrier needed)
    #pragma unroll
    for (int kc = 0; kc < 2; ++kc) {
      bf16x8 aP = *(const bf16x8*)(Pw + l16 * 72 + kc * 32 + quad * 8);
      const int pc = ((kc * 4 + quad) ^ (l16 & 7)) * 8;
      #pragma unroll
      for (int t = 0; t < 4; ++t) {
        bf16x8 bV = *(const bf16x8*)(&Vt[(16 * t + l16) * 64 + pc]);
        oacc[t] = mfma16x16x32(aP, bV, oacc[t]);
      }
    }
    // roll the C-init double buffer
    if (kt < 15) {
      #pragma unroll
      for (int t = 0; t < 4; ++t)
        #pragma unroll
        for (int r = 0; r < 4; ++r) cc[t][r] = nc[t][r];
    }
  }

  for (int r = 0; r < 4; ++r) {
    int row = qbase + quad * 4 + r;
    float inv = 1.0f / l_run[r];
    unsigned short* orow = attnw + (size_t)(b * S_ + row) * E_ + h * 64;
    for (int t = 0; t < 4; ++t)
      orow[16 * t + l16] = f2bf(oacc[t][r] * inv);
  }
}

// ---------------------------------------------------------------------------
// Workspace layout (bytes):
//   [0,16M) q bf16 | [16M,32M) k bf16 | [32M,48M) v^T bf16
//   [48M,64M) Xbf bf16 (during projections) THEN attn bf16 (time-disjoint)
//   [64M..72M) Wq/Wk/Wv/Wo bf16 (2 MB each) | [72M,+32K) maskadd f32
// ---------------------------------------------------------------------------
extern "C" void kernel_launch(void* const* d_in, const int* in_sizes, int n_in,
                              void* d_out, int out_size, void* d_ws, size_t ws_size,
                              hipStream_t stream) {
  const float* query      = (const float*)d_in[0];
  const float* attn_bias  = (const float*)d_in[3];
  const unsigned int* kpm = (const unsigned int*)d_in[4];
  const float* amask      = (const float*)d_in[5];
  const float* Wq = (const float*)d_in[9];
  const float* bq = (const float*)d_in[10];
  const float* Wk = (const float*)d_in[11];
  const float* bk = (const float*)d_in[12];
  const float* Wv = (const float*)d_in[13];
  const float* bv = (const float*)d_in[14];
  const float* Wo = (const float*)d_in[15];
  const float* bo = (const float*)d_in[16];

  char* ws = (char*)d_ws;
  const size_t MB16 = 16777216;
  unsigned short* qw    = (unsigned short*)(ws);
  unsigned short* kw    = (unsigned short*)(ws + MB16);
  unsigned short* vw    = (unsigned short*)(ws + 2 * MB16);
  unsigned short* xbf   = (unsigned short*)(ws + 3 * MB16);  // aliases attnw (time-disjoint)
  unsigned short* attnw = (unsigned short*)(ws + 3 * MB16);
  unsigned short* wqb   = (unsigned short*)(ws + 4 * MB16);
  unsigned short* wkb   = (unsigned short*)(ws + 4 * MB16 + 2097152);
  unsigned short* wvb   = (unsigned short*)(ws + 4 * MB16 + 2 * 2097152);
  unsigned short* wob   = (unsigned short*)(ws + 4 * MB16 + 3 * 2097152);
  float* maskadd        = (float*)(ws + 4 * MB16 + 4 * 2097152);

  mask_prep<<<1, 256, 0, stream>>>(kpm, maskadd);
  convert_prep<<<12288, 256, 0, stream>>>(query, Wq, Wk, Wv, Wo, xbf, wqb, wkb, wvb, wob);
  gemm_qkv<<<dim3(24, 64), 256, 0, stream>>>(xbf, wqb, wkb, wvb, bq, bk, bv, qw, kw, vw);
  attn_fwd<<<dim3(16, 128), 256, 0, stream>>>(qw, kw, vw, attn_bias, amask, maskadd, attnw);
  gemm_out<<<dim3(8, 64), 256, 0, stream>>>(attnw, wob, bo, (float*)d_out);
}